// Round 19
// baseline (1033.879 us; speedup 1.0000x reference)
//
#include <hip/hip_runtime.h>
#include <math.h>

#define BB    8
#define CC    64
#define NN    256
#define MM    20      // retained modes per axis
#define NKK   40      // retained row-modes: {0..19} U {236..255}
#define NLAY  3
#define FCD   128
#define PLANE (NN*NN)

// Fast tanh: clamp + exp-based. v_exp_f32/v_rcp_f32, ~1e-7 abs error, no branches.
__device__ __forceinline__ float fast_tanh(float x) {
    float xc = fminf(fmaxf(x, -15.f), 15.f);
    float e = __expf(2.f * xc);
    return (e - 1.f) / (e + 1.f);
}

// ---------------------------------------------------------------------------
// Basis precompute (double precision on device; tiny).
__global__ __launch_bounds__(256) void k_basis(float* __restrict__ FlT, float* __restrict__ FkT,
                                               float* __restrict__ BkT, float* __restrict__ BlT,
                                               float* __restrict__ CwT, const float* __restrict__ conv_w) {
    int t = threadIdx.x;
    const double PI = 3.14159265358979323846;
    for (int j = t; j < NN*MM; j += 256) {
        int y = j / MM, l = j % MM;
        double g = (y == 0 || y == NN-1) ? 1.0 : 2.0;
        FlT[j] = (float)(g * cos(PI * (double)(l*y) / (double)(NN-1)));
    }
    for (int j = t; j < NN*NKK; j += 256) {
        int x = j / NKK, k = j % NKK;
        int rk = (k < MM) ? k : (NN - NKK + k);
        double g = (x == 0 || x == NN-1) ? 1.0 : 2.0;
        FkT[j] = (float)(g * cos(PI * (double)(rk*x) / (double)(NN-1)));
    }
    for (int j = t; j < NKK*NN; j += 256) {
        int k = j / NN, p = j % NN;
        int rk = (k < MM) ? k : (NN - NKK + k);
        double g = (rk == 0 || rk == NN-1) ? 1.0 : 2.0;
        BkT[j] = (float)(g * cos(PI * (double)(rk*p) / (double)(NN-1)));
    }
    for (int j = t; j < MM*NN; j += 256) {
        int l = j / NN, q = j % NN;
        double g = (l == 0) ? 1.0 : 2.0;
        BlT[j] = (float)(g * cos(PI * (double)(q*l) / (double)(NN-1)));
    }
    for (int j = t; j < NLAY*CC*CC; j += 256) {
        int lay = j / (CC*CC), r = j % (CC*CC);
        int i = r / CC, o = r % CC;
        CwT[j] = conv_w[lay*CC*CC + o*CC + i];
    }
}

// ---------------------------------------------------------------------------
// fc0: h[b,c,p,q] = sum_d x[b,p,q,d]*w[d,c] + bias[c].  Block=(b,p), thread=q.
__global__ __launch_bounds__(256) void k_fc0(const float* __restrict__ xin, const float* __restrict__ w,
                                             const float* __restrict__ bias, float* __restrict__ h) {
    __shared__ float xs[NN*3];
    int b = blockIdx.x >> 8, p = blockIdx.x & 255, q = threadIdx.x;
    size_t rowbase = ((size_t)(b*NN + p)*NN) * 3;
    for (int j = q; j < NN*3; j += 256) xs[j] = xin[rowbase + j];
    __syncthreads();
    float v0 = xs[q*3+0], v1 = xs[q*3+1], v2 = xs[q*3+2];
    size_t obase = (size_t)b*CC*PLANE + (size_t)p*NN + q;
    #pragma unroll 8
    for (int c = 0; c < CC; ++c) {
        float hv = bias[c] + v0*w[c] + v1*w[CC+c] + v2*w[2*CC+c];
        h[obase + (size_t)c*PLANE] = hv;
    }
}

// ---------------------------------------------------------------------------
// Forward truncated DCT, ROUND-10 K-SPLIT (kept: total dropped 1123->1073).
__global__ __launch_bounds__(256, 4) void k_fwd(const float* __restrict__ h, const float* __restrict__ FkT,
                                                const float* __restrict__ FlT, float* __restrict__ Gt) {
    __shared__ float P[MM][NN+1];           // 20 x 257 floats = 20.6 KB
    int plane = blockIdx.x >> 1;            // b*CC + c
    int g = blockIdx.x & 1;                 // k-group: rows [20g, 20g+20)
    int t = threadIdx.x;
    const float* hp = h + (size_t)plane * PLANE;
    const float* fk = FkT + g*MM;           // this group's 20 columns of FkT rows
    float acc[MM];
    #pragma unroll
    for (int k = 0; k < MM; ++k) acc[k] = 0.f;
    #pragma unroll 4
    for (int x = 0; x < NN; ++x) {
        float hv = hp[x*NN + t];
        const float* fr = &fk[x*NKK];       // wave-uniform address -> s_load
        #pragma unroll
        for (int k = 0; k < MM; ++k) acc[k] += fr[k] * hv;
    }
    #pragma unroll
    for (int k = 0; k < MM; ++k) P[k][t] = acc[k];
    __syncthreads();
    int b = plane >> 6, c = plane & 63;
    for (int j = t; j < MM*MM; j += 256) {  // 400 outputs, 2 iters
        int kk = j / MM, l = j % MM;
        float a = 0.f;
        for (int y = 0; y < NN; ++y) a += P[kk][y] * FlT[y*MM + l];
        Gt[((size_t)((g*MM + kk)*BB + b)*CC + c)*MM + l] = a;
    }
}

// ---------------------------------------------------------------------------
// Spectral mode-mix: S[b,k,l,o] = sum_i G[b,i,kb,l] * w[i,o,kk,l].
// S layout [b][k][l][o] (o contiguous) for coalesced k_inv1 / wave-uniform U rows.
__global__ __launch_bounds__(256, 2) void k_spec(const float* __restrict__ Gt, const float* __restrict__ w1,
                                                 const float* __restrict__ w2, float* __restrict__ S) {
    extern __shared__ float gl[];           // BB*CC*MM = 10240 floats ([b][c][l] order)
    int kb = blockIdx.x;
    int t = threadIdx.x;
    const float* chunk = Gt + (size_t)kb * (BB*CC*MM);
    for (int j = t; j < BB*CC*MM; j += 256) gl[j] = chunk[j];
    __syncthreads();
    int o = t & 63, g = t >> 6;
    int b0 = 2*g, b1 = 2*g + 1;
    const float* wp; int kk;
    if (kb < MM) { wp = w1; kk = kb; } else { wp = w2; kk = kb - MM; }
    float a0[MM], a1[MM];
    #pragma unroll
    for (int l = 0; l < MM; ++l) { a0[l] = 0.f; a1[l] = 0.f; }
    for (int i = 0; i < CC; ++i) {
        const float4* wr4 = reinterpret_cast<const float4*>(wp + ((size_t)(i*CC + o)*MM + kk)*MM);
        const float4* g04 = reinterpret_cast<const float4*>(&gl[(b0*CC + i)*MM]);
        const float4* g14 = reinterpret_cast<const float4*>(&gl[(b1*CC + i)*MM]);
        #pragma unroll
        for (int l4 = 0; l4 < MM/4; ++l4) {
            float4 wv = wr4[l4];
            float4 gv0 = g04[l4];
            float4 gv1 = g14[l4];
            a0[4*l4+0] += wv.x*gv0.x; a0[4*l4+1] += wv.y*gv0.y;
            a0[4*l4+2] += wv.z*gv0.z; a0[4*l4+3] += wv.w*gv0.w;
            a1[4*l4+0] += wv.x*gv1.x; a1[4*l4+1] += wv.y*gv1.y;
            a1[4*l4+2] += wv.z*gv1.z; a1[4*l4+3] += wv.w*gv1.w;
        }
    }
    #pragma unroll
    for (int l = 0; l < MM; ++l) {
        S[((size_t)(b0*NKK + kb)*MM + l)*CC + o] = a0[l];   // coalesced in o
        S[((size_t)(b1*NKK + kb)*MM + l)*CC + o] = a1[l];
    }
}

// ---------------------------------------------------------------------------
// Inverse stage 1: U[b,p,l,o] = sum_k BkT[k,p] * S[b,k,l,o].
// ROUND-14: launched ONLY before the last layer (feeds the frozen monolith).
// Layers 0-1 get U fused into k_combine_inv instead (Phase A below).
__global__ __launch_bounds__(256, 2) void k_inv1(const float* __restrict__ S, const float* __restrict__ BkT,
                                                 float* __restrict__ U) {
    int b = blockIdx.x >> 8, p = blockIdx.x & 255;
    int o = threadIdx.x & 63, w = threadIdx.x >> 6;
    float acc[5];
    #pragma unroll
    for (int j = 0; j < 5; ++j) acc[j] = 0.f;
    for (int k = 0; k < NKK; ++k) {
        float bk = BkT[k*NN + p];                       // wave-uniform
        const float* sb = S + ((size_t)(b*NKK + k)*MM + w)*CC + o;
        #pragma unroll
        for (int j = 0; j < 5; ++j) acc[j] += bk * sb[(size_t)(4*j)*CC];
    }
    float* ub = U + ((size_t)(b*NN + p)*MM + w)*CC + o;
    #pragma unroll
    for (int j = 0; j < 5; ++j) ub[(size_t)(4*j)*CC] = acc[j];
}

// ---------------------------------------------------------------------------
// ROUND-14 FUSION: k_inv1 folded into combine for non-last layers.
// Phase A computes ul[l][o] = sum_k BkT[k,p]*S[b,k,l,o] into 5 KB LDS —
// EXACTLY k_inv1's work (same k-ascending order -> U bit-identical), 200
// FMA + 200 coalesced L2-resident S-loads per thread. Phase B is the r2
// combine body with the U row read from LDS (broadcast ds_read_b128) instead
// of a global s_load row. Non-split shape (2048 blocks, acc[64]): the r11
// qc-split was measured NEUTRAL (1073->1070) and would 4x the S traffic
// (1.7 GB/dispatch from L2, +49 µs). Saves: 2 k_inv1 dispatches (~30 µs
// each), 21 MB U round-trip, 2 launch gaps.
__global__ __launch_bounds__(256, 2) void k_combine_inv(float* h, const float* __restrict__ S,
                                                        const float* __restrict__ BkT,
                                                        const float* __restrict__ BlT,
                                                        const float* __restrict__ cwt,
                                                        const float* __restrict__ cb) {
    __shared__ float ul[MM*CC];             // 20 x 64 = 5 KB
    int b = blockIdx.x >> 8, p = blockIdx.x & 255;
    int t = threadIdx.x;
    // Phase A (k_inv1's math): 5 outputs/thread, 5 independent load chains.
    {
        float s[5];
        #pragma unroll
        for (int j = 0; j < 5; ++j) s[j] = 0.f;
        const float* sb = S + (size_t)b*NKK*MM*CC + t;
        for (int k = 0; k < NKK; ++k) {
            float bk = BkT[k*NN + p];                   // wave-uniform -> s_load
            const float* sk = sb + (size_t)k*MM*CC;
            #pragma unroll
            for (int j = 0; j < 5; ++j) s[j] += bk * sk[j*256];  // coalesced in t
        }
        #pragma unroll
        for (int j = 0; j < 5; ++j) ul[j*256 + t] = s[j];   // ul[idx]: l=idx>>6, o=idx&63
    }
    __syncthreads();
    // Phase B: r2 combine body; U row from LDS broadcast (float4).
    int q = t;
    float acc[CC];
    #pragma unroll
    for (int o = 0; o < CC; ++o) acc[o] = cb[o];
    float* hb = h + (size_t)b*CC*PLANE + (size_t)p*NN + q;
    #pragma unroll 4
    for (int i = 0; i < CC; ++i) {
        float hv = hb[(size_t)i*PLANE];
        const float* wr = &cwt[i*CC];                   // wave-uniform -> s_load
        #pragma unroll
        for (int o = 0; o < CC; ++o) acc[o] += wr[o]*hv;
    }
    #pragma unroll 2
    for (int l = 0; l < MM; ++l) {
        float blv = BlT[l*NN + q];
        const float4* u4 = reinterpret_cast<const float4*>(&ul[l*CC]);  // broadcast b128
        #pragma unroll
        for (int o4 = 0; o4 < CC/4; ++o4) {
            float4 uv = u4[o4];
            acc[4*o4+0] += uv.x*blv; acc[4*o4+1] += uv.y*blv;
            acc[4*o4+2] += uv.z*blv; acc[4*o4+3] += uv.w*blv;
        }
    }
    #pragma unroll
    for (int o = 0; o < CC; ++o) hb[(size_t)o*PLANE] = fast_tanh(acc[o]);
}

// ---------------------------------------------------------------------------
// Last layer: the round-2 monolith (measured 243 µs, VALUBusy 82% — best
// measured last-layer). FROZEN — reads global U from the single remaining
// k_inv1 dispatch. Its AGPR round-trips empirically hide the strided h-load
// latency (r3/r4 lesson: "fixing" them regressed 243->446).
__global__ __launch_bounds__(256, 2) void k_combine_fc(const float* __restrict__ h, const float* __restrict__ U,
        const float* __restrict__ BlT, const float* __restrict__ cwt, const float* __restrict__ cb,
        const float* __restrict__ w1, const float* __restrict__ b1,
        const float* __restrict__ w2, const float* __restrict__ b2, float* __restrict__ out) {
    int b = blockIdx.x >> 8, p = blockIdx.x & 255;
    int q = threadIdx.x;
    float acc[CC];
    #pragma unroll
    for (int o = 0; o < CC; ++o) acc[o] = cb[o];
    const float* hb = h + (size_t)b*CC*PLANE + (size_t)p*NN + q;
    #pragma unroll 4
    for (int i = 0; i < CC; ++i) {
        float hv = hb[(size_t)i*PLANE];
        const float* wr = &cwt[i*CC];                   // wave-uniform -> s_load
        #pragma unroll
        for (int o = 0; o < CC; ++o) acc[o] += wr[o]*hv;
    }
    const float* ub = U + ((size_t)(b*NN + p)*MM)*CC;
    #pragma unroll 2
    for (int l = 0; l < MM; ++l) {
        float blv = BlT[l*NN + q];
        const float* ur = ub + (size_t)l*CC;
        #pragma unroll
        for (int o = 0; o < CC; ++o) acc[o] += ur[o]*blv;
    }
    // fc1 -> tanh -> fc2 on the in-register channel vector
    float ov = b2[0];
    const int FCH = 8;
    for (int f0 = 0; f0 < FCD; f0 += FCH) {
        float a[FCH];
        #pragma unroll
        for (int f = 0; f < FCH; ++f) a[f] = b1[f0 + f];
        #pragma unroll                                  // FULL unroll: acc[i] constant-indexed
        for (int i = 0; i < CC; ++i) {
            float hv = acc[i];
            const float* wr = &w1[i*FCD + f0];          // wave-uniform -> s_load
            #pragma unroll
            for (int f = 0; f < FCH; ++f) a[f] += hv*wr[f];
        }
        #pragma unroll
        for (int f = 0; f < FCH; ++f) ov += fast_tanh(a[f]) * w2[f0 + f];
    }
    out[(size_t)blockIdx.x*NN + q] = ov;
}

// ---------------------------------------------------------------------------
extern "C" void kernel_launch(void* const* d_in, const int* in_sizes, int n_in,
                              void* d_out, int out_size, void* d_ws, size_t ws_size,
                              hipStream_t stream) {
    const float* x      = (const float*)d_in[0];
    const float* fc0_w  = (const float*)d_in[1];
    const float* fc0_b  = (const float*)d_in[2];
    const float* sp_w1  = (const float*)d_in[3];
    const float* sp_w2  = (const float*)d_in[4];
    const float* conv_w = (const float*)d_in[5];
    const float* conv_b = (const float*)d_in[6];
    const float* fc1_w  = (const float*)d_in[7];
    const float* fc1_b  = (const float*)d_in[8];
    const float* fc2_w  = (const float*)d_in[9];
    const float* fc2_b  = (const float*)d_in[10];

    float* ws = (float*)d_ws;
    const size_t HSZ = (size_t)BB*CC*PLANE;           // 33,554,432 floats (134.2 MB)
    float* hA  = ws;
    float* Gt  = hA + HSZ;                            // NKK*BB*CC*MM = 409,600
    float* S   = Gt + (size_t)NKK*BB*CC*MM;           // BB*NKK*MM*CC = 409,600
    float* U   = S  + (size_t)BB*NKK*MM*CC;           // BB*NN*MM*CC  = 2,621,440
    float* FlT = U  + (size_t)BB*NN*MM*CC;            // NN*MM   =  5,120
    float* FkT = FlT + NN*MM;                         // NN*NKK  = 10,240
    float* BkT = FkT + NN*NKK;                        // NKK*NN  = 10,240
    float* BlT = BkT + NKK*NN;                        // MM*NN   =  5,120
    float* CwT = BlT + MM*NN;                         // NLAY*CC*CC = 12,288
    // total = 37,038,080 floats = 148.2 MB of workspace

    k_basis<<<1, 256, 0, stream>>>(FlT, FkT, BkT, BlT, CwT, conv_w);
    k_fc0<<<BB*NN, 256, 0, stream>>>(x, fc0_w, fc0_b, hA);

    for (int lay = 0; lay < NLAY; ++lay) {
        const float* w1 = sp_w1 + (size_t)lay*CC*CC*MM*MM;
        const float* w2 = sp_w2 + (size_t)lay*CC*CC*MM*MM;
        k_fwd<<<BB*CC*2, 256, 0, stream>>>(hA, FkT, FlT, Gt);
        k_spec<<<NKK, 256, BB*CC*MM*sizeof(float), stream>>>(Gt, w1, w2, S);
        if (lay != NLAY-1) {
            // k_inv1 fused into combine (Phase A) — no U round-trip.
            k_combine_inv<<<BB*NN, 256, 0, stream>>>(
                hA, S, BkT, BlT, CwT + lay*CC*CC, conv_b + lay*CC);
        } else {
            k_inv1<<<BB*NN, 256, 0, stream>>>(S, BkT, U);
            k_combine_fc<<<BB*NN, 256, 0, stream>>>(
                hA, U, BlT, CwT + lay*CC*CC, conv_b + lay*CC,
                fc1_w, fc1_b, fc2_w, fc2_b, (float*)d_out);
        }
    }
}

// Round 20
// 886.451 us; speedup vs baseline: 1.1663x; 1.1663x over previous
//
#include <hip/hip_runtime.h>
#include <math.h>

#define BB    8
#define CC    64
#define NN    256
#define MM    20      // retained modes per axis
#define NKK   40      // retained row-modes: {0..19} U {236..255}
#define NLAY  3
#define FCD   128
#define PLANE (NN*NN)

// Fast tanh: clamp + exp-based. v_exp_f32/v_rcp_f32, ~1e-7 abs error, no branches.
__device__ __forceinline__ float fast_tanh(float x) {
    float xc = fminf(fmaxf(x, -15.f), 15.f);
    float e = __expf(2.f * xc);
    return (e - 1.f) / (e + 1.f);
}

// ---------------------------------------------------------------------------
// Basis precompute (double precision on device; tiny).
__global__ __launch_bounds__(256) void k_basis(float* __restrict__ FlT, float* __restrict__ FkT,
                                               float* __restrict__ BkT, float* __restrict__ BlT,
                                               float* __restrict__ CwT, const float* __restrict__ conv_w) {
    int t = threadIdx.x;
    const double PI = 3.14159265358979323846;
    for (int j = t; j < NN*MM; j += 256) {
        int y = j / MM, l = j % MM;
        double g = (y == 0 || y == NN-1) ? 1.0 : 2.0;
        FlT[j] = (float)(g * cos(PI * (double)(l*y) / (double)(NN-1)));
    }
    for (int j = t; j < NN*NKK; j += 256) {
        int x = j / NKK, k = j % NKK;
        int rk = (k < MM) ? k : (NN - NKK + k);
        double g = (x == 0 || x == NN-1) ? 1.0 : 2.0;
        FkT[j] = (float)(g * cos(PI * (double)(rk*x) / (double)(NN-1)));
    }
    for (int j = t; j < NKK*NN; j += 256) {
        int k = j / NN, p = j % NN;
        int rk = (k < MM) ? k : (NN - NKK + k);
        double g = (rk == 0 || rk == NN-1) ? 1.0 : 2.0;
        BkT[j] = (float)(g * cos(PI * (double)(rk*p) / (double)(NN-1)));
    }
    for (int j = t; j < MM*NN; j += 256) {
        int l = j / NN, q = j % NN;
        double g = (l == 0) ? 1.0 : 2.0;
        BlT[j] = (float)(g * cos(PI * (double)(q*l) / (double)(NN-1)));
    }
    for (int j = t; j < NLAY*CC*CC; j += 256) {
        int lay = j / (CC*CC), r = j % (CC*CC);
        int i = r / CC, o = r % CC;
        CwT[j] = conv_w[lay*CC*CC + o*CC + i];
    }
}

// ---------------------------------------------------------------------------
// fc0: h[b,c,p,q] = sum_d x[b,p,q,d]*w[d,c] + bias[c].  Block=(b,p), thread=q.
__global__ __launch_bounds__(256) void k_fc0(const float* __restrict__ xin, const float* __restrict__ w,
                                             const float* __restrict__ bias, float* __restrict__ h) {
    __shared__ float xs[NN*3];
    int b = blockIdx.x >> 8, p = blockIdx.x & 255, q = threadIdx.x;
    size_t rowbase = ((size_t)(b*NN + p)*NN) * 3;
    for (int j = q; j < NN*3; j += 256) xs[j] = xin[rowbase + j];
    __syncthreads();
    float v0 = xs[q*3+0], v1 = xs[q*3+1], v2 = xs[q*3+2];
    size_t obase = (size_t)b*CC*PLANE + (size_t)p*NN + q;
    #pragma unroll 8
    for (int c = 0; c < CC; ++c) {
        float hv = bias[c] + v0*w[c] + v1*w[CC+c] + v2*w[2*CC+c];
        h[obase + (size_t)c*PLANE] = hv;
    }
}

// ---------------------------------------------------------------------------
// Forward truncated DCT, ROUND-10 K-SPLIT (kept: total dropped 1123->1073).
__global__ __launch_bounds__(256, 4) void k_fwd(const float* __restrict__ h, const float* __restrict__ FkT,
                                                const float* __restrict__ FlT, float* __restrict__ Gt) {
    __shared__ float P[MM][NN+1];           // 20 x 257 floats = 20.6 KB
    int plane = blockIdx.x >> 1;            // b*CC + c
    int g = blockIdx.x & 1;                 // k-group: rows [20g, 20g+20)
    int t = threadIdx.x;
    const float* hp = h + (size_t)plane * PLANE;
    const float* fk = FkT + g*MM;           // this group's 20 columns of FkT rows
    float acc[MM];
    #pragma unroll
    for (int k = 0; k < MM; ++k) acc[k] = 0.f;
    #pragma unroll 4
    for (int x = 0; x < NN; ++x) {
        float hv = hp[x*NN + t];
        const float* fr = &fk[x*NKK];       // wave-uniform address -> s_load
        #pragma unroll
        for (int k = 0; k < MM; ++k) acc[k] += fr[k] * hv;
    }
    #pragma unroll
    for (int k = 0; k < MM; ++k) P[k][t] = acc[k];
    __syncthreads();
    int b = plane >> 6, c = plane & 63;
    for (int j = t; j < MM*MM; j += 256) {  // 400 outputs, 2 iters
        int kk = j / MM, l = j % MM;
        float a = 0.f;
        for (int y = 0; y < NN; ++y) a += P[kk][y] * FlT[y*MM + l];
        Gt[((size_t)((g*MM + kk)*BB + b)*CC + c)*MM + l] = a;
    }
}

// ---------------------------------------------------------------------------
// Spectral mode-mix — ROUND-19 REGRID. Old shape: 40 blocks on 256 CUs =
// 84% of the GPU idle by construction. New: grid (kb, b) = 320 blocks;
// each block stages ONE batch element's G chunk (5 KB LDS, was 40 KB);
// wave w owns l in [5w, 5w+5), lane = o. Per-output i-ascending sum
// preserved -> bit-identical S. Cost: 8 b-blocks per kb re-read the same
// 327 KB weight rows (L2/L3-hot; 26 MB/layer fits L3) — cheap vs 6.4x
// more CUs working. G reads from LDS are wave-uniform -> broadcast.
__global__ __launch_bounds__(256, 2) void k_spec(const float* __restrict__ Gt, const float* __restrict__ w1,
                                                 const float* __restrict__ w2, float* __restrict__ S) {
    __shared__ float gl[CC*MM];             // one b's G chunk: 1280 floats = 5 KB
    int kb = blockIdx.x >> 3;               // 0..39
    int b  = blockIdx.x & 7;                // 0..7
    int t = threadIdx.x;
    const float* chunk = Gt + ((size_t)kb*BB + b) * (CC*MM);   // [c][l] for this (kb,b)
    for (int j = t; j < CC*MM; j += 256) gl[j] = chunk[j];
    __syncthreads();
    int o = t & 63, w = t >> 6;
    int l0 = w*5;                           // wave-uniform l-range
    const float* wp; int kk;
    if (kb < MM) { wp = w1; kk = kb; } else { wp = w2; kk = kb - MM; }
    float a[5];
    #pragma unroll
    for (int j = 0; j < 5; ++j) a[j] = 0.f;
    for (int i = 0; i < CC; ++i) {
        const float* wr = wp + ((size_t)(i*CC + o)*MM + kk)*MM + l0;
        const float* gr = &gl[i*MM + l0];   // wave-uniform -> LDS broadcast
        a[0] += wr[0]*gr[0]; a[1] += wr[1]*gr[1]; a[2] += wr[2]*gr[2];
        a[3] += wr[3]*gr[3]; a[4] += wr[4]*gr[4];
    }
    #pragma unroll
    for (int j = 0; j < 5; ++j)
        S[((size_t)(b*NKK + kb)*MM + (l0+j))*CC + o] = a[j];   // coalesced in o
}

// ---------------------------------------------------------------------------
// Inverse stage 1: U[b,p,l,o] = sum_k BkT[k,p] * S[b,k,l,o].
// ROUND-19: restored x3 per layer. The r14 fusion into combine REGRESSED
// (993 -> 1034): k_inv1's latency-bound 40-iter S-walk ran fine at its own
// high occupancy (tiny VGPR, 8 blocks/CU) but stalled inside the fat
// acc[64] combine (~3 blocks/CU) behind a __syncthreads. Lesson: don't
// move latency-bound phases into low-occupancy kernels.
__global__ __launch_bounds__(256, 2) void k_inv1(const float* __restrict__ S, const float* __restrict__ BkT,
                                                 float* __restrict__ U) {
    int b = blockIdx.x >> 8, p = blockIdx.x & 255;
    int o = threadIdx.x & 63, w = threadIdx.x >> 6;
    float acc[5];
    #pragma unroll
    for (int j = 0; j < 5; ++j) acc[j] = 0.f;
    for (int k = 0; k < NKK; ++k) {
        float bk = BkT[k*NN + p];                       // wave-uniform
        const float* sb = S + ((size_t)(b*NKK + k)*MM + w)*CC + o;
        #pragma unroll
        for (int j = 0; j < 5; ++j) acc[j] += bk * sb[(size_t)(4*j)*CC];
    }
    float* ub = U + ((size_t)(b*NN + p)*MM + w)*CC + o;
    #pragma unroll
    for (int j = 0; j < 5; ++j) ub[(size_t)(4*j)*CC] = acc[j];
}

// ---------------------------------------------------------------------------
// Combine IN PLACE — ROUND-11 WAVE-SPLIT (part of the measured-993 config).
__global__ __launch_bounds__(256, 4) void k_combine(float* h, const float* __restrict__ U,
                                                    const float* __restrict__ BlT, const float* __restrict__ cwt,
                                                    const float* __restrict__ cb) {
    int qc = blockIdx.x & 3;
    int p  = (blockIdx.x >> 2) & 255;
    int b  = blockIdx.x >> 10;
    int lane = threadIdx.x & 63;
    int w = __builtin_amdgcn_readfirstlane(threadIdx.x >> 6);
    int q = qc*64 + lane;
    int o0 = w*16;
    float acc[16];
    #pragma unroll
    for (int oo = 0; oo < 16; ++oo) acc[oo] = cb[o0 + oo];
    float* hb = h + (size_t)b*CC*PLANE + (size_t)p*NN + q;
    #pragma unroll 4
    for (int i = 0; i < CC; ++i) {
        float hv = hb[(size_t)i*PLANE];                 // coalesced; waves share rows via L1
        const float* wr = &cwt[i*CC + o0];              // uniform -> s_load
        #pragma unroll
        for (int oo = 0; oo < 16; ++oo) acc[oo] += wr[oo]*hv;
    }
    const float* ub = U + ((size_t)(b*NN + p)*MM)*CC + o0;
    #pragma unroll 4
    for (int l = 0; l < MM; ++l) {
        float blv = BlT[l*NN + q];
        const float* ur = ub + (size_t)l*CC;            // uniform row -> s_load
        #pragma unroll
        for (int oo = 0; oo < 16; ++oo) acc[oo] += ur[oo]*blv;
    }
    __syncthreads();    // all waves' h reads drained before any in-place write
    #pragma unroll
    for (int oo = 0; oo < 16; ++oo) hb[(size_t)(o0 + oo)*PLANE] = fast_tanh(acc[oo]);
}

// ---------------------------------------------------------------------------
// Last layer: the round-2 monolith (measured 243-245 µs, VALUBusy 82% —
// best measured last-layer). FROZEN.
__global__ __launch_bounds__(256, 2) void k_combine_fc(const float* __restrict__ h, const float* __restrict__ U,
        const float* __restrict__ BlT, const float* __restrict__ cwt, const float* __restrict__ cb,
        const float* __restrict__ w1, const float* __restrict__ b1,
        const float* __restrict__ w2, const float* __restrict__ b2, float* __restrict__ out) {
    int b = blockIdx.x >> 8, p = blockIdx.x & 255;
    int q = threadIdx.x;
    float acc[CC];
    #pragma unroll
    for (int o = 0; o < CC; ++o) acc[o] = cb[o];
    const float* hb = h + (size_t)b*CC*PLANE + (size_t)p*NN + q;
    #pragma unroll 4
    for (int i = 0; i < CC; ++i) {
        float hv = hb[(size_t)i*PLANE];
        const float* wr = &cwt[i*CC];                   // wave-uniform -> s_load
        #pragma unroll
        for (int o = 0; o < CC; ++o) acc[o] += wr[o]*hv;
    }
    const float* ub = U + ((size_t)(b*NN + p)*MM)*CC;
    #pragma unroll 2
    for (int l = 0; l < MM; ++l) {
        float blv = BlT[l*NN + q];
        const float* ur = ub + (size_t)l*CC;
        #pragma unroll
        for (int o = 0; o < CC; ++o) acc[o] += ur[o]*blv;
    }
    // fc1 -> tanh -> fc2 on the in-register channel vector
    float ov = b2[0];
    const int FCH = 8;
    for (int f0 = 0; f0 < FCD; f0 += FCH) {
        float a[FCH];
        #pragma unroll
        for (int f = 0; f < FCH; ++f) a[f] = b1[f0 + f];
        #pragma unroll                                  // FULL unroll: acc[i] constant-indexed
        for (int i = 0; i < CC; ++i) {
            float hv = acc[i];
            const float* wr = &w1[i*FCD + f0];          // wave-uniform -> s_load
            #pragma unroll
            for (int f = 0; f < FCH; ++f) a[f] += hv*wr[f];
        }
        #pragma unroll
        for (int f = 0; f < FCH; ++f) ov += fast_tanh(a[f]) * w2[f0 + f];
    }
    out[(size_t)blockIdx.x*NN + q] = ov;
}

// ---------------------------------------------------------------------------
extern "C" void kernel_launch(void* const* d_in, const int* in_sizes, int n_in,
                              void* d_out, int out_size, void* d_ws, size_t ws_size,
                              hipStream_t stream) {
    const float* x      = (const float*)d_in[0];
    const float* fc0_w  = (const float*)d_in[1];
    const float* fc0_b  = (const float*)d_in[2];
    const float* sp_w1  = (const float*)d_in[3];
    const float* sp_w2  = (const float*)d_in[4];
    const float* conv_w = (const float*)d_in[5];
    const float* conv_b = (const float*)d_in[6];
    const float* fc1_w  = (const float*)d_in[7];
    const float* fc1_b  = (const float*)d_in[8];
    const float* fc2_w  = (const float*)d_in[9];
    const float* fc2_b  = (const float*)d_in[10];

    float* ws = (float*)d_ws;
    const size_t HSZ = (size_t)BB*CC*PLANE;           // 33,554,432 floats (134.2 MB)
    float* hA  = ws;
    float* Gt  = hA + HSZ;                            // NKK*BB*CC*MM = 409,600
    float* S   = Gt + (size_t)NKK*BB*CC*MM;           // BB*NKK*MM*CC = 409,600
    float* U   = S  + (size_t)BB*NKK*MM*CC;           // BB*NN*MM*CC  = 2,621,440
    float* FlT = U  + (size_t)BB*NN*MM*CC;            // NN*MM   =  5,120
    float* FkT = FlT + NN*MM;                         // NN*NKK  = 10,240
    float* BkT = FkT + NN*NKK;                        // NKK*NN  = 10,240
    float* BlT = BkT + NKK*NN;                        // MM*NN   =  5,120
    float* CwT = BlT + MM*NN;                         // NLAY*CC*CC = 12,288
    // total = 37,038,080 floats = 148.2 MB of workspace

    k_basis<<<1, 256, 0, stream>>>(FlT, FkT, BkT, BlT, CwT, conv_w);
    k_fc0<<<BB*NN, 256, 0, stream>>>(x, fc0_w, fc0_b, hA);

    for (int lay = 0; lay < NLAY; ++lay) {
        const float* w1 = sp_w1 + (size_t)lay*CC*CC*MM*MM;
        const float* w2 = sp_w2 + (size_t)lay*CC*CC*MM*MM;
        k_fwd<<<BB*CC*2, 256, 0, stream>>>(hA, FkT, FlT, Gt);
        k_spec<<<NKK*BB, 256, 0, stream>>>(Gt, w1, w2, S);
        k_inv1<<<BB*NN, 256, 0, stream>>>(S, BkT, U);
        if (lay != NLAY-1) {
            k_combine<<<BB*NN*4, 256, 0, stream>>>(
                hA, U, BlT, CwT + lay*CC*CC, conv_b + lay*CC);
        } else {
            k_combine_fc<<<BB*NN, 256, 0, stream>>>(
                hA, U, BlT, CwT + lay*CC*CC, conv_b + lay*CC,
                fc1_w, fc1_b, fc2_w, fc2_b, (float*)d_out);
        }
    }
}